// Round 9
// baseline (2037.378 us; speedup 1.0000x reference)
//
#include <hip/hip_runtime.h>
#include <math.h>

#define BATCH 256
#define LEN   10000
#define C0 64
#define P0 624
#define T1 155
#define P1 77

// ws offsets (in floats)
#define OFF_CONST 0
#define OFF_BAR   160        // barrier slot lines: 8 groups x 32 members x 64B = 16KB
#define OFF_Y1    2560160
#define OFF_X     12783776
#define OFF_H0    15306912
#define OFF_C0    15437984
#define OFF_H1    15503520
#define OFF_C1    15634592
#define OFF_Z0    15700128
#define OFF_Z1    15831200
#define OFF_TMP   15962272

// ---------------- host-side savgol constants ----------------
static void invert4(const double A[4][4], double inv[4][4]) {
  double M[4][8];
  for (int i = 0; i < 4; ++i)
    for (int j = 0; j < 4; ++j) { M[i][j] = A[i][j]; M[i][j+4] = (i==j) ? 1.0 : 0.0; }
  for (int col = 0; col < 4; ++col) {
    int p = col;
    for (int r = col+1; r < 4; ++r) if (fabs(M[r][col]) > fabs(M[p][col])) p = r;
    if (p != col) for (int j = 0; j < 8; ++j) { double t = M[col][j]; M[col][j] = M[p][j]; M[p][j] = t; }
    double d = M[col][col];
    for (int j = 0; j < 8; ++j) M[col][j] /= d;
    for (int r = 0; r < 4; ++r) if (r != col) {
      double f = M[r][col];
      for (int j = 0; j < 8; ++j) M[r][j] -= f * M[col][j];
    }
  }
  for (int i = 0; i < 4; ++i) for (int j = 0; j < 4; ++j) inv[i][j] = M[i][j+4];
}

static void compute_consts(float* out) {
  {
    double V[11][4], A[4][4], inv[4][4];
    for (int w = 0; w < 11; ++w) { double t = (double)(w-5), pw = 1.0; for (int m = 0; m < 4; ++m) { V[w][m] = pw; pw *= t; } }
    for (int m = 0; m < 4; ++m) for (int n = 0; n < 4; ++n) { double s = 0; for (int w = 0; w < 11; ++w) s += V[w][m]*V[w][n]; A[m][n] = s; }
    invert4(A, inv);
    for (int w = 0; w < 11; ++w) { double s = 0; for (int m = 0; m < 4; ++m) s += inv[0][m]*V[w][m]; out[w] = (float)s; }
  }
  {
    double V[11][4], A[4][4], inv[4][4], pe[4][11];
    for (int w = 0; w < 11; ++w) { double t = (double)w, pw = 1.0; for (int m = 0; m < 4; ++m) { V[w][m] = pw; pw *= t; } }
    for (int m = 0; m < 4; ++m) for (int n = 0; n < 4; ++n) { double s = 0; for (int w = 0; w < 11; ++w) s += V[w][m]*V[w][n]; A[m][n] = s; }
    invert4(A, inv);
    for (int m = 0; m < 4; ++m) for (int w = 0; w < 11; ++w) { double s = 0; for (int n = 0; n < 4; ++n) s += inv[m][n]*V[w][n]; pe[m][w] = s; }
    for (int w = 0; w < 11; ++w) for (int k = 0; k < 5; ++k) {
      double s = 0, pk = 1.0;
      for (int m = 0; m < 4; ++m) { s += pe[m][w]*pk; pk *= (double)k; }
      out[16 + w*5 + k] = (float)s;
    }
    for (int w = 0; w < 11; ++w) for (int k = 0; k < 5; ++k) {
      double tv = (double)(6+k), s = 0, pk = 1.0;
      for (int m = 0; m < 4; ++m) { s += pe[m][w]*pk; pk *= tv; }
      out[80 + w*5 + k] = (float)s;
    }
  }
}

// ---------------- fused savgol + conv0 + relu + pool2 + bn: x -> y1 (256,64,624) ----------------
__global__ __launch_bounds__(256) void k_sgconv0(const float* __restrict__ x,
    const float* __restrict__ Cc,
    const float* __restrict__ w0, const float* __restrict__ cb0,
    const float* __restrict__ bg0, const float* __restrict__ bb0,
    const float* __restrict__ bm0, const float* __restrict__ bv0,
    float* __restrict__ y1) {
  __shared__ float sw[1024];
  __shared__ float s_sc[64], s_off[64], s_cb[64];
  int tid = threadIdx.x;
  for (int i = tid; i < 1024; i += 256) sw[i] = w0[i];
  if (tid < 64) {
    float sc = bg0[tid] * rsqrtf(bv0[tid] + 1e-5f);
    s_sc[tid] = sc;
    s_off[tid] = bb0[tid] - bm0[tid]*sc;
    s_cb[tid] = cb0[tid];
  }
  __syncthreads();
  int b = blockIdx.y;
  int uu = blockIdx.x*256 + tid;
  if (uu >= P0) return;
  const float* xb = x + b*LEN;
  float hC[11];
#pragma unroll
  for (int w = 0; w < 11; ++w) hC[w] = Cc[w];
  float iv[24];
  if (uu == 0) {
    float xx[32];
    const float4* p = reinterpret_cast<const float4*>(xb);
#pragma unroll
    for (int j = 0; j < 8; ++j) { float4 v = p[j]; xx[4*j]=v.x; xx[4*j+1]=v.y; xx[4*j+2]=v.z; xx[4*j+3]=v.w; }
#pragma unroll
    for (int j = 0; j < 24; ++j) {
      float s = 0.f;
      if (j < 5) {
        for (int w = 0; w < 11; ++w) s += xx[w] * Cc[16 + w*5 + j];
      } else {
        for (int w = 0; w < 11; ++w) s += xx[j-5+w] * hC[w];
      }
      iv[j] = s;
    }
  } else {
    float xx[40];
    const float4* p = reinterpret_cast<const float4*>(xb + 16*uu - 8);
#pragma unroll
    for (int j = 0; j < 10; ++j) { float4 v = p[j]; xx[4*j]=v.x; xx[4*j+1]=v.y; xx[4*j+2]=v.z; xx[4*j+3]=v.w; }
#pragma unroll
    for (int j = 0; j < 24; ++j) {
      float s = 0.f;
#pragma unroll
      for (int w = 0; w < 11; ++w) s += xx[j+3+w] * hC[w];
      iv[j] = s;
    }
  }
  int obase = b*(C0*P0) + uu;
  for (int oc = 0; oc < 64; ++oc) {
    float bias = s_cb[oc];
    float s0 = bias, s1 = bias;
#pragma unroll
    for (int k = 0; k < 16; ++k) {
      float wk = sw[oc*16 + k];
      s0 += iv[k]   * wk;
      s1 += iv[k+8] * wk;
    }
    float pm = fmaxf(fmaxf(s0, 0.f), fmaxf(s1, 0.f));
    y1[obase + oc*P0] = pm*s_sc[oc] + s_off[oc];
  }
}

// ---------------- conv1 as im2col GEMM: 64m x 128n tiles, K=512, 620 blocks ----------------
__global__ __launch_bounds__(256) void k_conv1_gemm(const float* __restrict__ y1,
    const float* __restrict__ w1, const float* __restrict__ cb1,
    float* __restrict__ tmp) {
  __shared__ __align__(16) float a_t[32*66];
  __shared__ __align__(16) float w_t[32*132];
  int m0 = blockIdx.x * 64;
  int tid = threadIdx.x;
  int sa_s = tid & 7, sa_r = tid >> 3;
  int un = tid & 31, mq = tid >> 5;
  int ybase[2];
#pragma unroll
  for (int i = 0; i < 2; ++i) {
    int m = m0 + sa_r + 32*i;
    int b = m / 155, t = m - b*155;
    ybase[i] = b*(C0*P0) + 4*t;
  }
  int ci_off = sa_s >> 1, kkq = (sa_s & 1) * 4;
  float4 av[2], wv[4];
  float acc[8][4] = {{0.f}};
  int swzw = sa_s << 2;

#define CONV1_PREFETCH(cidx) do {                                                   \
    int kc = (cidx) * 32;                                                           \
    int ci0 = kc >> 3;                                                              \
    av[0] = *reinterpret_cast<const float4*>(y1 + ybase[0] + (ci0 + ci_off)*P0 + kkq); \
    av[1] = *reinterpret_cast<const float4*>(y1 + ybase[1] + (ci0 + ci_off)*P0 + kkq); \
    _Pragma("unroll")                                                               \
    for (int i = 0; i < 4; ++i)                                                     \
      wv[i] = *reinterpret_cast<const float4*>(w1 + (sa_r + 32*i)*512 + kc + 4*sa_s); \
  } while (0)

  CONV1_PREFETCH(0);
  for (int cidx = 0; cidx < 16; ++cidx) {
    if (cidx) __syncthreads();
#pragma unroll
    for (int i = 0; i < 2; ++i) {
      int col = sa_r + 32*i;
      a_t[(4*sa_s+0)*66 + col] = av[i].x;
      a_t[(4*sa_s+1)*66 + col] = av[i].y;
      a_t[(4*sa_s+2)*66 + col] = av[i].z;
      a_t[(4*sa_s+3)*66 + col] = av[i].w;
    }
#pragma unroll
    for (int i = 0; i < 4; ++i) {
      int colw = (sa_r + 32*i) ^ swzw;
      w_t[(4*sa_s+0)*132 + colw] = wv[i].x;
      w_t[(4*sa_s+1)*132 + colw] = wv[i].y;
      w_t[(4*sa_s+2)*132 + colw] = wv[i].z;
      w_t[(4*sa_s+3)*132 + colw] = wv[i].w;
    }
    __syncthreads();
    if (cidx + 1 < 16) { CONV1_PREFETCH(cidx + 1); }
#pragma unroll
    for (int k = 0; k < 32; ++k) {
      float4 w4 = *reinterpret_cast<const float4*>(&w_t[k*132 + ((4*un) ^ ((k>>2)<<2))]);
      float2 a2[4];
#pragma unroll
      for (int i = 0; i < 4; ++i)
        a2[i] = *reinterpret_cast<const float2*>(&a_t[k*66 + 2*mq + 16*i]);
#pragma unroll
      for (int i = 0; i < 4; ++i) {
        acc[2*i+0][0] += a2[i].x*w4.x; acc[2*i+0][1] += a2[i].x*w4.y;
        acc[2*i+0][2] += a2[i].x*w4.z; acc[2*i+0][3] += a2[i].x*w4.w;
        acc[2*i+1][0] += a2[i].y*w4.x; acc[2*i+1][1] += a2[i].y*w4.y;
        acc[2*i+1][2] += a2[i].y*w4.z; acc[2*i+1][3] += a2[i].y*w4.w;
      }
    }
  }
#undef CONV1_PREFETCH
  float4 bias = *reinterpret_cast<const float4*>(cb1 + 4*un);
#pragma unroll
  for (int i = 0; i < 4; ++i)
#pragma unroll
    for (int jj = 0; jj < 2; ++jj) {
      int m = m0 + 2*mq + 16*i + jj;
      float4 o;
      o.x = acc[2*i+jj][0] + bias.x;
      o.y = acc[2*i+jj][1] + bias.y;
      o.z = acc[2*i+jj][2] + bias.z;
      o.w = acc[2*i+jj][3] + bias.w;
      *reinterpret_cast<float4*>(tmp + m*128 + 4*un) = o;
    }
}

// ---------------- relu + pool2 + bn: tmp -> X (77,256,128) t-major ----------------
__global__ __launch_bounds__(256) void k_pool1(const float* __restrict__ tmp,
    const float* __restrict__ bg1, const float* __restrict__ bb1,
    const float* __restrict__ bm1, const float* __restrict__ bv1,
    float* __restrict__ X) {
  int idx = blockIdx.x*256 + threadIdx.x;
  int u  = idx >> 15;
  int rr = idx & 32767;
  int bb = rr >> 7;
  int oc = rr & 127;
  int base = (bb*155 + 2*u)*128 + oc;
  float t0 = tmp[base], t1 = tmp[base + 128];
  float pm = fmaxf(0.f, fmaxf(t0, t1));
  float sc = bg1[oc] * rsqrtf(bv1[oc] + 1e-5f);
  X[idx] = pm*sc + (bb1[oc] - bm1[oc]*sc);
}

// ---------------- persistent LSTM v5: 256 blocks x 512 threads (8 waves = 2/SIMD) ----------------
// r8 counters (v4c, 4 waves = 1/SIMD): persist 1628us (20.9us/step), VALUBusy 19.3%,
// Occupancy 12.1%, bank-conflict 0. VALU wall ~4us matches 19.3%; LDS throughput wall
// ~9us; the 2.3x gap is LDS latency exposure with NO second wave per SIMD to cover
// lgkmcnt stalls. v5: 8 waves/block (2/SIMD) -> TLP covers LDS latency.
// Waves split K 8-ways (KW = 64/48). A staged per-wave, SINGLE-buffered 8k x 32b
// (same-wave DS ops process in order, so reads of sc complete before writes of sc+1
// pass them -- dbuf was unnecessary). Full-step A-prefetch: all NSC float4 loads
// issued back-to-back into registers at step start (8x16B in flight/wave, vs 2).
// All register-array loops fully unrolled + guarded (avr[j] compile-time indexed).
// LDS: W 128KB + A 8KB + red 8KB = 144KB -> 1 block/CU, all 256 resident.
// Reduction: 8-phase sequential chain w7->...->w0; wave0 holds c in regs, activates,
// writes h. Barrier unchanged (slot lines, wave0 32-lane gather poll, proven r8).
__global__ __launch_bounds__(512) void k_lstm_persist(
    const float* __restrict__ X,
    const float* __restrict__ Wih0, const float* __restrict__ Whh0,
    const float* __restrict__ bih0, const float* __restrict__ bhh0,
    const float* __restrict__ Wih1, const float* __restrict__ Whh1,
    const float* __restrict__ bih1, const float* __restrict__ bhh1,
    float* __restrict__ h0buf, float* __restrict__ h1buf,
    unsigned* bar) {
  __shared__ __align__(16) float w_lds[512*64];   // [k][col], col = 4*ulocal + gate (128KB)
  __shared__ __align__(16) float a_lds[8*8*32];   // per-wave [8k][32b] (8KB)
  __shared__ __align__(16) float red[2048];       // reduction buffer (8KB)

  const int blk  = blockIdx.x;
  const int g    = blk & 7;          // b-tile / barrier group
  const int role = blk >> 3;         // 0..31
  const int layer = role >> 4;
  const int u0   = (role & 15) * 16;
  const int b0   = g * 32;
  const int tid  = threadIdx.x;
  const int wv   = tid >> 6;         // 0..7
  const int lane = tid & 63;
  const int bq   = lane >> 3;        // batches b0 + 4*bq + {0..3}
  const int rq   = lane & 7;         // cols 8*rq + {0..7}
  const int K    = layer ? 512 : 384;
  const int KW   = K >> 3;           // per-wave K range: 64 / 48
  const int k0w  = wv * KW;
  const int NSC  = KW >> 3;          // 8-k sub-chunks per wave: 8 / 6

  // ---- one-time W staging: [k][64col], col c -> global row (c&3)*256 + u0 + (c>>2) ----
  {
    const int c = tid & 63;
    const int kq4 = (tid >> 6) << 2;   // 8 groups x 4 k each per 32-k block
    const int row = (c & 3)*256 + u0 + (c >> 2);
    for (int kb = 0; kb < K; kb += 32) {
      const int kg = kb + kq4;
      const float* wp; int wstr, woff;
      if (layer == 0) {
        if (kg < 128) { wp = Wih0; wstr = 128; woff = kg; }
        else          { wp = Whh0; wstr = 256; woff = kg - 128; }
      } else {
        if (kg < 256) { wp = Wih1; wstr = 256; woff = kg; }
        else          { wp = Whh1; wstr = 256; woff = kg - 256; }
      }
      float4 v = *reinterpret_cast<const float4*>(wp + row*wstr + woff);
      w_lds[(kg+0)*64 + c] = v.x;
      w_lds[(kg+1)*64 + c] = v.y;
      w_lds[(kg+2)*64 + c] = v.z;
      w_lds[(kg+3)*64 + c] = v.w;
    }
  }

  // biases + persistent cell state (used by wave 0 only)
  const float* bi_p = layer ? bih1 : bih0;
  const float* bh_p = layer ? bhh1 : bhh0;
  float bsum[2][4];
#pragma unroll
  for (int uj = 0; uj < 2; ++uj) {
    const int uu = u0 + 2*rq + uj;
#pragma unroll
    for (int gt = 0; gt < 4; ++gt)
      bsum[uj][gt] = bi_p[gt*256 + uu] + bh_p[gt*256 + uu];
  }
  float c_reg[2][4] = {{0.f,0.f,0.f,0.f},{0.f,0.f,0.f,0.f}};

  float* aw = a_lds + (wv << 8);     // wave-private 256-float region
  const int bl = lane & 31, jq = lane >> 5;
  unsigned* slot = bar + ((g*32 + role) << 4);
  unsigned* gbase = bar + ((g*32) << 4);

  float4 avr[8];
#define PF_SC(j, ss) do {                                                         \
    const int kc_ = k0w + 8*(j);                                                  \
    const float* ap; int astr, aoff;                                              \
    if (layer == 0) {                                                             \
      if (kc_ < 128) { ap = X + (ss)*32768;              astr = 128; aoff = kc_; }       \
      else           { ap = h0buf + ((ss)&1)*65536;      astr = 256; aoff = kc_ - 128; } \
    } else {                                                                      \
      if (kc_ < 256) { ap = h0buf + ((ss)&1)*65536;      astr = 256; aoff = kc_; }       \
      else           { ap = h1buf + ((ss)&1)*65536;      astr = 256; aoff = kc_ - 256; } \
    }                                                                             \
    avr[j] = *reinterpret_cast<const float4*>(ap + (b0 + bl)*astr + aoff + 4*jq); \
  } while (0)

  // # of X-sourced (immutable, pre-barrier-loadable) sub-chunks for this wave
  int nXc = 0;
  if (layer == 0) { nXc = (128 - k0w) >> 3; if (nXc < 0) nXc = 0; if (nXc > NSC) nXc = NSC; }
  const int nX = nXc;

  // prologue: X-sourced sub-chunks for s=0 (layer 0 only)
  if (layer == 0) {
#pragma unroll
    for (int j = 0; j < 6; ++j) if (j < nX) PF_SC(j, 0);
  }

  __syncthreads();   // w_lds ready

#define STEP_COMPUTE(NSCC) do {                                                   \
    _Pragma("unroll")                                                             \
    for (int j = 0; j < (NSCC); ++j) if (j >= nX) PF_SC(j, s);                    \
    _Pragma("unroll")                                                             \
    for (int sc = 0; sc < (NSCC); ++sc) {                                         \
      aw[(4*jq+0)*32 + bl] = avr[sc].x;                                           \
      aw[(4*jq+1)*32 + bl] = avr[sc].y;                                           \
      aw[(4*jq+2)*32 + bl] = avr[sc].z;                                           \
      aw[(4*jq+3)*32 + bl] = avr[sc].w;                                           \
      const float* wk = w_lds + ((k0w + (sc << 3)) << 6);                         \
      _Pragma("unroll")                                                           \
      for (int kl = 0; kl < 8; ++kl) {                                            \
        const float4 a4 = *reinterpret_cast<const float4*>(aw + kl*32 + 4*bq);    \
        const float4 wA = *reinterpret_cast<const float4*>(wk + (kl<<6) + 8*rq);  \
        const float4 wB = *reinterpret_cast<const float4*>(wk + (kl<<6) + 8*rq + 4); \
        acc[0][0] += a4.x*wA.x; acc[0][1] += a4.x*wA.y; acc[0][2] += a4.x*wA.z; acc[0][3] += a4.x*wA.w; \
        acc[0][4] += a4.x*wB.x; acc[0][5] += a4.x*wB.y; acc[0][6] += a4.x*wB.z; acc[0][7] += a4.x*wB.w; \
        acc[1][0] += a4.y*wA.x; acc[1][1] += a4.y*wA.y; acc[1][2] += a4.y*wA.z; acc[1][3] += a4.y*wA.w; \
        acc[1][4] += a4.y*wB.x; acc[1][5] += a4.y*wB.y; acc[1][6] += a4.y*wB.z; acc[1][7] += a4.y*wB.w; \
        acc[2][0] += a4.z*wA.x; acc[2][1] += a4.z*wA.y; acc[2][2] += a4.z*wA.z; acc[2][3] += a4.z*wA.w; \
        acc[2][4] += a4.z*wB.x; acc[2][5] += a4.z*wB.y; acc[2][6] += a4.z*wB.z; acc[2][7] += a4.z*wB.w; \
        acc[3][0] += a4.w*wA.x; acc[3][1] += a4.w*wA.y; acc[3][2] += a4.w*wA.z; acc[3][3] += a4.w*wA.w; \
        acc[3][4] += a4.w*wB.x; acc[3][5] += a4.w*wB.y; acc[3][6] += a4.w*wB.z; acc[3][7] += a4.w*wB.w; \
      }                                                                           \
    }                                                                             \
  } while (0)

#pragma unroll 1
  for (int s = 0; s <= 77; ++s) {
    const bool active = layer ? (s >= 1) : (s < 77);
    if (active) {
      float acc[4][8];
#pragma unroll
      for (int i = 0; i < 4; ++i)
#pragma unroll
        for (int j = 0; j < 8; ++j) acc[i][j] = 0.f;

      if (layer == 0) { STEP_COMPUTE(6); } else { STEP_COMPUTE(8); }

      // ---- 8-wave sequential K reduction: w7 -> w6 -> ... -> w0 ----
      __syncthreads();
      if (wv == 7) {
#pragma unroll
        for (int qi = 0; qi < 8; ++qi) {
          const int bi = qi >> 1, c0 = (qi & 1) << 2;
          *reinterpret_cast<float4*>(&red[((qi<<6) + lane) << 2]) =
            make_float4(acc[bi][c0], acc[bi][c0+1], acc[bi][c0+2], acc[bi][c0+3]);
        }
      }
#pragma unroll 1
      for (int rw = 6; rw >= 1; --rw) {
        __syncthreads();
        if (wv == rw) {
#pragma unroll
          for (int qi = 0; qi < 8; ++qi) {
            const int bi = qi >> 1, c0 = (qi & 1) << 2;
            float4 v = *reinterpret_cast<const float4*>(&red[((qi<<6) + lane) << 2]);
            *reinterpret_cast<float4*>(&red[((qi<<6) + lane) << 2]) =
              make_float4(acc[bi][c0]+v.x, acc[bi][c0+1]+v.y, acc[bi][c0+2]+v.z, acc[bi][c0+3]+v.w);
          }
        }
      }
      __syncthreads();
      if (wv == 0) {
#pragma unroll
        for (int qi = 0; qi < 8; ++qi) {
          const int bi = qi >> 1, c0 = (qi & 1) << 2;
          float4 v = *reinterpret_cast<const float4*>(&red[((qi<<6) + lane) << 2]);
          acc[bi][c0]   += v.x;
          acc[bi][c0+1] += v.y;
          acc[bi][c0+2] += v.z;
          acc[bi][c0+3] += v.w;
        }
        float* __restrict__ hw = (layer ? h1buf : h0buf) + ((s+1)&1)*65536;
#pragma unroll
        for (int bi = 0; bi < 4; ++bi) {
          float hv[2];
#pragma unroll
          for (int uj = 0; uj < 2; ++uj) {
            float gi = acc[bi][4*uj+0] + bsum[uj][0];
            float gf = acc[bi][4*uj+1] + bsum[uj][1];
            float gg = acc[bi][4*uj+2] + bsum[uj][2];
            float go = acc[bi][4*uj+3] + bsum[uj][3];
            float si = 1.f/(1.f + expf(-gi));
            float sf = 1.f/(1.f + expf(-gf));
            float so = 1.f/(1.f + expf(-go));
            float tg = tanhf(gg);
            float cn = sf*c_reg[uj][bi] + si*tg;
            c_reg[uj][bi] = cn;
            hv[uj] = so*tanhf(cn);
          }
          *reinterpret_cast<float2*>(hw + (b0 + 4*bq + bi)*256 + u0 + 2*rq) =
            make_float2(hv[0], hv[1]);
        }
        __threadfence();            // release: wave0's h-writes visible device-wide
      }
    }
    if (s == 77) break;
    if (tid == 0)
      __hip_atomic_store(slot, (unsigned)(s+1), __ATOMIC_RELEASE, __HIP_MEMORY_SCOPE_AGENT);
    // pre-spin prefetch of next step's X-sourced sub-chunks (immutable, race-free)
    if (layer == 0 && s + 1 < 77) {
#pragma unroll
      for (int j = 0; j < 6; ++j) if (j < nX) PF_SC(j, s + 1);
    }
    if (wv == 0) {
      const unsigned tgt = (unsigned)(s+1);
      for (;;) {
        unsigned v = tgt;
        if (lane < 32)
          v = __hip_atomic_load(gbase + (lane << 4), __ATOMIC_RELAXED, __HIP_MEMORY_SCOPE_AGENT);
        if (__all(v >= tgt)) break;
        __builtin_amdgcn_s_sleep(2);
      }
      __threadfence();              // acquire: invalidate stale L1/L2 before h reads
    }
    __syncthreads();
  }
#undef STEP_COMPUTE
#undef PF_SC
}

// ---------------- FC: C = act(A @ W^T + b), M=256 ----------------
__global__ __launch_bounds__(256) void k_fc(const float* __restrict__ A,
    const float* __restrict__ W, const float* __restrict__ bias,
    float* __restrict__ Cout, int N, int K, int kshift, int dorelu) {
  __shared__ __align__(16) float sa[16*516];
  int m0 = blockIdx.y * 16;
  int n = blockIdx.x * 16 + (threadIdx.x & 15);
  int m = threadIdx.x >> 4;
  int stride = K + 4;
  for (int i = threadIdx.x; i < 16*K; i += 256) {
    int mm = i >> kshift;
    int kk = i - (mm << kshift);
    sa[mm*stride + kk] = A[(m0+mm)*K + kk];
  }
  __syncthreads();
  const float4* wr = reinterpret_cast<const float4*>(W + n*K);
  const float4* ar = reinterpret_cast<const float4*>(sa + m*stride);
  float acc = 0.f;
  int kq4 = K >> 2;
  for (int kq = 0; kq < kq4; ++kq) {
    float4 wv = wr[kq], av = ar[kq];
    acc += av.x*wv.x + av.y*wv.y + av.z*wv.z + av.w*wv.w;
  }
  acc += bias[n];
  if (dorelu) acc = fmaxf(acc, 0.f);
  Cout[(m0+m)*N + n] = acc;
}

extern "C" void kernel_launch(void* const* d_in, const int* in_sizes, int n_in,
                              void* d_out, int out_size, void* d_ws, size_t ws_size,
                              hipStream_t stream) {
  const float* x       = (const float*)d_in[0];
  const float* conv_w0 = (const float*)d_in[1];
  const float* conv_b0 = (const float*)d_in[2];
  const float* bn_g0   = (const float*)d_in[3];
  const float* bn_b0   = (const float*)d_in[4];
  const float* bn_m0   = (const float*)d_in[5];
  const float* bn_v0   = (const float*)d_in[6];
  const float* conv_w1 = (const float*)d_in[7];
  const float* conv_b1 = (const float*)d_in[8];
  const float* bn_g1   = (const float*)d_in[9];
  const float* bn_b1   = (const float*)d_in[10];
  const float* bn_m1   = (const float*)d_in[11];
  const float* bn_v1   = (const float*)d_in[12];
  const float* Wih0    = (const float*)d_in[13];
  const float* Whh0    = (const float*)d_in[14];
  const float* bih0    = (const float*)d_in[15];
  const float* bhh0    = (const float*)d_in[16];
  const float* Wih1    = (const float*)d_in[17];
  const float* Whh1    = (const float*)d_in[18];
  const float* bih1    = (const float*)d_in[19];
  const float* bhh1    = (const float*)d_in[20];
  const float* fc0_w   = (const float*)d_in[21];
  const float* fc0_b   = (const float*)d_in[22];
  const float* fc1_w   = (const float*)d_in[23];
  const float* fc1_b   = (const float*)d_in[24];
  const float* out_w   = (const float*)d_in[25];
  const float* out_b   = (const float*)d_in[26];
  float* ws = (float*)d_ws;
  float* out = (float*)d_out;

  static float h_consts[160];
  compute_consts(h_consts);
  hipMemcpyAsync(ws + OFF_CONST, h_consts, 160*sizeof(float), hipMemcpyHostToDevice, stream);
  hipMemsetAsync(ws + OFF_H0, 0, 393216*sizeof(float), stream);
  hipMemsetAsync(ws + OFF_BAR, 0, 16384, stream);   // barrier slot lines -> 0

  k_sgconv0<<<dim3(3, BATCH), 256, 0, stream>>>(x, ws + OFF_CONST, conv_w0, conv_b0,
                                                bn_g0, bn_b0, bn_m0, bn_v0, ws + OFF_Y1);
  k_conv1_gemm<<<620, 256, 0, stream>>>(ws + OFF_Y1, conv_w1, conv_b1, ws + OFF_TMP);
  k_pool1<<<9856, 256, 0, stream>>>(ws + OFF_TMP, bn_g1, bn_b1, bn_m1, bn_v1, ws + OFF_X);
  k_lstm_persist<<<256, 512, 0, stream>>>(ws + OFF_X, Wih0, Whh0, bih0, bhh0,
                                          Wih1, Whh1, bih1, bhh1,
                                          ws + OFF_H0, ws + OFF_H1,
                                          (unsigned*)(ws + OFF_BAR));
  k_fc<<<dim3(32, 16), 256, 0, stream>>>(ws + OFF_H1, fc0_w, fc0_b, ws + OFF_Z0, 512, 256, 8, 1);
  k_fc<<<dim3(32, 16), 256, 0, stream>>>(ws + OFF_Z0, fc1_w, fc1_b, ws + OFF_Z1, 512, 512, 9, 1);
  k_fc<<<dim3(16, 16), 256, 0, stream>>>(ws + OFF_Z1, out_w, out_b, out, 256, 512, 9, 0);
}

// Round 11
// 1175.759 us; speedup vs baseline: 1.7328x; 1.7328x over previous
//
#include <hip/hip_runtime.h>
#include <math.h>

#define BATCH 256
#define LEN   10000
#define C0 64
#define P0 624
#define T1 155
#define P1 77

// ws offsets (in floats)
#define OFF_CONST 0
#define OFF_BAR   160        // barrier slot lines: 8 groups x 32 members x 64B = 16KB
#define OFF_Y1    2560160
#define OFF_X     12783776
#define OFF_H0    15306912
#define OFF_C0    15437984
#define OFF_H1    15503520
#define OFF_C1    15634592
#define OFF_Z0    15700128
#define OFF_Z1    15831200
#define OFF_TMP   15962272

// ---------------- host-side savgol constants ----------------
static void invert4(const double A[4][4], double inv[4][4]) {
  double M[4][8];
  for (int i = 0; i < 4; ++i)
    for (int j = 0; j < 4; ++j) { M[i][j] = A[i][j]; M[i][j+4] = (i==j) ? 1.0 : 0.0; }
  for (int col = 0; col < 4; ++col) {
    int p = col;
    for (int r = col+1; r < 4; ++r) if (fabs(M[r][col]) > fabs(M[p][col])) p = r;
    if (p != col) for (int j = 0; j < 8; ++j) { double t = M[col][j]; M[col][j] = M[p][j]; M[p][j] = t; }
    double d = M[col][col];
    for (int j = 0; j < 8; ++j) M[col][j] /= d;
    for (int r = 0; r < 4; ++r) if (r != col) {
      double f = M[r][col];
      for (int j = 0; j < 8; ++j) M[r][j] -= f * M[col][j];
    }
  }
  for (int i = 0; i < 4; ++i) for (int j = 0; j < 4; ++j) inv[i][j] = M[i][j+4];
}

static void compute_consts(float* out) {
  {
    double V[11][4], A[4][4], inv[4][4];
    for (int w = 0; w < 11; ++w) { double t = (double)(w-5), pw = 1.0; for (int m = 0; m < 4; ++m) { V[w][m] = pw; pw *= t; } }
    for (int m = 0; m < 4; ++m) for (int n = 0; n < 4; ++n) { double s = 0; for (int w = 0; w < 11; ++w) s += V[w][m]*V[w][n]; A[m][n] = s; }
    invert4(A, inv);
    for (int w = 0; w < 11; ++w) { double s = 0; for (int m = 0; m < 4; ++m) s += inv[0][m]*V[w][m]; out[w] = (float)s; }
  }
  {
    double V[11][4], A[4][4], inv[4][4], pe[4][11];
    for (int w = 0; w < 11; ++w) { double t = (double)w, pw = 1.0; for (int m = 0; m < 4; ++m) { V[w][m] = pw; pw *= t; } }
    for (int m = 0; m < 4; ++m) for (int n = 0; n < 4; ++n) { double s = 0; for (int w = 0; w < 11; ++w) s += V[w][m]*V[w][n]; A[m][n] = s; }
    invert4(A, inv);
    for (int m = 0; m < 4; ++m) for (int w = 0; w < 11; ++w) { double s = 0; for (int n = 0; n < 4; ++n) s += inv[m][n]*V[w][n]; pe[m][w] = s; }
    for (int w = 0; w < 11; ++w) for (int k = 0; k < 5; ++k) {
      double s = 0, pk = 1.0;
      for (int m = 0; m < 4; ++m) { s += pe[m][w]*pk; pk *= (double)k; }
      out[16 + w*5 + k] = (float)s;
    }
    for (int w = 0; w < 11; ++w) for (int k = 0; k < 5; ++k) {
      double tv = (double)(6+k), s = 0, pk = 1.0;
      for (int m = 0; m < 4; ++m) { s += pe[m][w]*pk; pk *= tv; }
      out[80 + w*5 + k] = (float)s;
    }
  }
}

// ---------------- fused savgol + conv0 + relu + pool2 + bn: x -> y1 (256,64,624) ----------------
__global__ __launch_bounds__(256) void k_sgconv0(const float* __restrict__ x,
    const float* __restrict__ Cc,
    const float* __restrict__ w0, const float* __restrict__ cb0,
    const float* __restrict__ bg0, const float* __restrict__ bb0,
    const float* __restrict__ bm0, const float* __restrict__ bv0,
    float* __restrict__ y1) {
  __shared__ float sw[1024];
  __shared__ float s_sc[64], s_off[64], s_cb[64];
  int tid = threadIdx.x;
  for (int i = tid; i < 1024; i += 256) sw[i] = w0[i];
  if (tid < 64) {
    float sc = bg0[tid] * rsqrtf(bv0[tid] + 1e-5f);
    s_sc[tid] = sc;
    s_off[tid] = bb0[tid] - bm0[tid]*sc;
    s_cb[tid] = cb0[tid];
  }
  __syncthreads();
  int b = blockIdx.y;
  int uu = blockIdx.x*256 + tid;
  if (uu >= P0) return;
  const float* xb = x + b*LEN;
  float hC[11];
#pragma unroll
  for (int w = 0; w < 11; ++w) hC[w] = Cc[w];
  float iv[24];
  if (uu == 0) {
    float xx[32];
    const float4* p = reinterpret_cast<const float4*>(xb);
#pragma unroll
    for (int j = 0; j < 8; ++j) { float4 v = p[j]; xx[4*j]=v.x; xx[4*j+1]=v.y; xx[4*j+2]=v.z; xx[4*j+3]=v.w; }
#pragma unroll
    for (int j = 0; j < 24; ++j) {
      float s = 0.f;
      if (j < 5) {
        for (int w = 0; w < 11; ++w) s += xx[w] * Cc[16 + w*5 + j];
      } else {
        for (int w = 0; w < 11; ++w) s += xx[j-5+w] * hC[w];
      }
      iv[j] = s;
    }
  } else {
    float xx[40];
    const float4* p = reinterpret_cast<const float4*>(xb + 16*uu - 8);
#pragma unroll
    for (int j = 0; j < 10; ++j) { float4 v = p[j]; xx[4*j]=v.x; xx[4*j+1]=v.y; xx[4*j+2]=v.z; xx[4*j+3]=v.w; }
#pragma unroll
    for (int j = 0; j < 24; ++j) {
      float s = 0.f;
#pragma unroll
      for (int w = 0; w < 11; ++w) s += xx[j+3+w] * hC[w];
      iv[j] = s;
    }
  }
  int obase = b*(C0*P0) + uu;
  for (int oc = 0; oc < 64; ++oc) {
    float bias = s_cb[oc];
    float s0 = bias, s1 = bias;
#pragma unroll
    for (int k = 0; k < 16; ++k) {
      float wk = sw[oc*16 + k];
      s0 += iv[k]   * wk;
      s1 += iv[k+8] * wk;
    }
    float pm = fmaxf(fmaxf(s0, 0.f), fmaxf(s1, 0.f));
    y1[obase + oc*P0] = pm*s_sc[oc] + s_off[oc];
  }
}

// ---------------- conv1 as im2col GEMM: 64m x 128n tiles, K=512, 620 blocks ----------------
__global__ __launch_bounds__(256) void k_conv1_gemm(const float* __restrict__ y1,
    const float* __restrict__ w1, const float* __restrict__ cb1,
    float* __restrict__ tmp) {
  __shared__ __align__(16) float a_t[32*66];
  __shared__ __align__(16) float w_t[32*132];
  int m0 = blockIdx.x * 64;
  int tid = threadIdx.x;
  int sa_s = tid & 7, sa_r = tid >> 3;
  int un = tid & 31, mq = tid >> 5;
  int ybase[2];
#pragma unroll
  for (int i = 0; i < 2; ++i) {
    int m = m0 + sa_r + 32*i;
    int b = m / 155, t = m - b*155;
    ybase[i] = b*(C0*P0) + 4*t;
  }
  int ci_off = sa_s >> 1, kkq = (sa_s & 1) * 4;
  float4 av[2], wv[4];
  float acc[8][4] = {{0.f}};
  int swzw = sa_s << 2;

#define CONV1_PREFETCH(cidx) do {                                                   \
    int kc = (cidx) * 32;                                                           \
    int ci0 = kc >> 3;                                                              \
    av[0] = *reinterpret_cast<const float4*>(y1 + ybase[0] + (ci0 + ci_off)*P0 + kkq); \
    av[1] = *reinterpret_cast<const float4*>(y1 + ybase[1] + (ci0 + ci_off)*P0 + kkq); \
    _Pragma("unroll")                                                               \
    for (int i = 0; i < 4; ++i)                                                     \
      wv[i] = *reinterpret_cast<const float4*>(w1 + (sa_r + 32*i)*512 + kc + 4*sa_s); \
  } while (0)

  CONV1_PREFETCH(0);
  for (int cidx = 0; cidx < 16; ++cidx) {
    if (cidx) __syncthreads();
#pragma unroll
    for (int i = 0; i < 2; ++i) {
      int col = sa_r + 32*i;
      a_t[(4*sa_s+0)*66 + col] = av[i].x;
      a_t[(4*sa_s+1)*66 + col] = av[i].y;
      a_t[(4*sa_s+2)*66 + col] = av[i].z;
      a_t[(4*sa_s+3)*66 + col] = av[i].w;
    }
#pragma unroll
    for (int i = 0; i < 4; ++i) {
      int colw = (sa_r + 32*i) ^ swzw;
      w_t[(4*sa_s+0)*132 + colw] = wv[i].x;
      w_t[(4*sa_s+1)*132 + colw] = wv[i].y;
      w_t[(4*sa_s+2)*132 + colw] = wv[i].z;
      w_t[(4*sa_s+3)*132 + colw] = wv[i].w;
    }
    __syncthreads();
    if (cidx + 1 < 16) { CONV1_PREFETCH(cidx + 1); }
#pragma unroll
    for (int k = 0; k < 32; ++k) {
      float4 w4 = *reinterpret_cast<const float4*>(&w_t[k*132 + ((4*un) ^ ((k>>2)<<2))]);
      float2 a2[4];
#pragma unroll
      for (int i = 0; i < 4; ++i)
        a2[i] = *reinterpret_cast<const float2*>(&a_t[k*66 + 2*mq + 16*i]);
#pragma unroll
      for (int i = 0; i < 4; ++i) {
        acc[2*i+0][0] += a2[i].x*w4.x; acc[2*i+0][1] += a2[i].x*w4.y;
        acc[2*i+0][2] += a2[i].x*w4.z; acc[2*i+0][3] += a2[i].x*w4.w;
        acc[2*i+1][0] += a2[i].y*w4.x; acc[2*i+1][1] += a2[i].y*w4.y;
        acc[2*i+1][2] += a2[i].y*w4.z; acc[2*i+1][3] += a2[i].y*w4.w;
      }
    }
  }
#undef CONV1_PREFETCH
  float4 bias = *reinterpret_cast<const float4*>(cb1 + 4*un);
#pragma unroll
  for (int i = 0; i < 4; ++i)
#pragma unroll
    for (int jj = 0; jj < 2; ++jj) {
      int m = m0 + 2*mq + 16*i + jj;
      float4 o;
      o.x = acc[2*i+jj][0] + bias.x;
      o.y = acc[2*i+jj][1] + bias.y;
      o.z = acc[2*i+jj][2] + bias.z;
      o.w = acc[2*i+jj][3] + bias.w;
      *reinterpret_cast<float4*>(tmp + m*128 + 4*un) = o;
    }
}

// ---------------- relu + pool2 + bn: tmp -> X (77,256,128) t-major ----------------
__global__ __launch_bounds__(256) void k_pool1(const float* __restrict__ tmp,
    const float* __restrict__ bg1, const float* __restrict__ bb1,
    const float* __restrict__ bm1, const float* __restrict__ bv1,
    float* __restrict__ X) {
  int idx = blockIdx.x*256 + threadIdx.x;
  int u  = idx >> 15;
  int rr = idx & 32767;
  int bb = rr >> 7;
  int oc = rr & 127;
  int base = (bb*155 + 2*u)*128 + oc;
  float t0 = tmp[base], t1 = tmp[base + 128];
  float pm = fmaxf(0.f, fmaxf(t0, t1));
  float sc = bg1[oc] * rsqrtf(bv1[oc] + 1e-5f);
  X[idx] = pm*sc + (bb1[oc] - bm1[oc]*sc);
}

// ---- fence-free h exchange: relaxed AGENT-scope 8B atomics (sc1, bypass per-XCD L2,
// coherent at L3). Same mechanism as the (proven) slot barrier. No buffer_wbl2 /
// buffer_inv anywhere in the step loop. ----
__device__ __forceinline__ float2 h_load2(const float* p) {
  unsigned long long v = __hip_atomic_load((const unsigned long long*)p,
                                           __ATOMIC_RELAXED, __HIP_MEMORY_SCOPE_AGENT);
  float2 r;
  r.x = __uint_as_float((unsigned)v);
  r.y = __uint_as_float((unsigned)(v >> 32));
  return r;
}
__device__ __forceinline__ void h_store2(float* p, float a, float b) {
  unsigned long long v = (unsigned long long)__float_as_uint(a)
                       | ((unsigned long long)__float_as_uint(b) << 32);
  __hip_atomic_store((unsigned long long*)p, v,
                     __ATOMIC_RELAXED, __HIP_MEMORY_SCOPE_AGENT);
}

// ---------------- persistent LSTM v6: V4c structure + fence-free h-exchange ----------------
// r8 (V4c, fences): persist 1628us (20.9us/step), VALUBusy 19.3%. r9 (V5, 8 waves):
// 1870us -- occupancy doubled but time rose => TLP was NOT the bottleneck. Revised
// theory: the per-step __threadfence pair forces L2 writeback (release) + invalidate
// (acquire) on non-coherent per-XCD L2s -- ~13us/step of cache maintenance, identical
// in V4c/V5. v6 = V4c with ONE change: h reads/writes become relaxed agent-scope 8B
// atomics (sc1 -> chip-coherent L3), both fences deleted. Ordering: wave0's h-stores
// are drained by the vmcnt(0) __syncthreads emits before s_barrier; slot release
// follows in wave0 program order. Consumers poll slots (sc1-fresh), compiler barrier,
// __syncthreads, then sc1 h-loads. L1/L2 now stay warm for X across steps.
// Everything else (4 waves, K 4-way split, dbuf A, 4-phase reduction, slot barrier,
// c-in-registers, W LDS-stationary 128KB, pf_early X prefetch) is byte-identical to r8.
__global__ __launch_bounds__(256) void k_lstm_persist(
    const float* __restrict__ X,
    const float* __restrict__ Wih0, const float* __restrict__ Whh0,
    const float* __restrict__ bih0, const float* __restrict__ bhh0,
    const float* __restrict__ Wih1, const float* __restrict__ Whh1,
    const float* __restrict__ bih1, const float* __restrict__ bhh1,
    float* __restrict__ h0buf, float* __restrict__ h1buf,
    unsigned* bar) {
  __shared__ __align__(16) float w_lds[512*64];   // [k][col], col = 4*ulocal + gate
  __shared__ __align__(16) float a_lds[4*2*16*32];// per-wave 2x [16k][32b] (dbuf)
  __shared__ __align__(16) float red[2048];       // reduction buffer (one wave's acc)

  const int blk  = blockIdx.x;
  const int g    = blk & 7;          // b-tile / barrier group
  const int role = blk >> 3;         // 0..31
  const int layer = role >> 4;
  const int u0   = (role & 15) * 16;
  const int b0   = g * 32;
  const int tid  = threadIdx.x;
  const int wv   = tid >> 6;
  const int lane = tid & 63;
  const int bq   = lane >> 3;        // batches b0 + 4*bq + {0..3}
  const int rq   = lane & 7;         // cols 8*rq + {0..7}
  const int K    = layer ? 512 : 384;
  const int KW   = K >> 2;           // per-wave K range
  const int k0w  = wv * KW;
  const int NSC  = KW >> 4;          // 16-k sub-chunks per wave: 8 / 6

  // ---- one-time W staging: [k][64col], col c -> global row (c&3)*256 + u0 + (c>>2) ----
  {
    const int c = tid & 63;
    const int kq4 = (tid >> 6) << 2;
    const int row = (c & 3)*256 + u0 + (c >> 2);
    for (int kb = 0; kb < K; kb += 16) {
      const int kg = kb + kq4;
      const float* wp; int wstr, woff;
      if (layer == 0) {
        if (kg < 128) { wp = Wih0; wstr = 128; woff = kg; }
        else          { wp = Whh0; wstr = 256; woff = kg - 128; }
      } else {
        if (kg < 256) { wp = Wih1; wstr = 256; woff = kg; }
        else          { wp = Whh1; wstr = 256; woff = kg - 256; }
      }
      float4 v = *reinterpret_cast<const float4*>(wp + row*wstr + woff);
      w_lds[(kg+0)*64 + c] = v.x;
      w_lds[(kg+1)*64 + c] = v.y;
      w_lds[(kg+2)*64 + c] = v.z;
      w_lds[(kg+3)*64 + c] = v.w;
    }
  }

  // biases + persistent cell state (used by wave 0 only)
  const float* bi_p = layer ? bih1 : bih0;
  const float* bh_p = layer ? bhh1 : bhh0;
  float bsum[2][4];
#pragma unroll
  for (int uj = 0; uj < 2; ++uj) {
    const int uu = u0 + 2*rq + uj;
#pragma unroll
    for (int gt = 0; gt < 4; ++gt)
      bsum[uj][gt] = bi_p[gt*256 + uu] + bh_p[gt*256 + uu];
  }
  float c_reg[2][4] = {{0.f,0.f,0.f,0.f},{0.f,0.f,0.f,0.f}};

  float* aw = a_lds + (wv << 10);    // wave-private 1024-float region (2 halves)
  const int bl = lane & 31, jq = lane >> 5;
  unsigned* slot = bar + ((g*32 + role) << 4);
  unsigned* gbase = bar + ((g*32) << 4);

  float4 av0, av1;
#define PF_A(kcg, ss) do {                                                        \
    const int kc_ = (kcg);                                                        \
    const float* ap; int astr, aoff; bool at_;                                    \
    if (layer == 0) {                                                             \
      if (kc_ < 128) { ap = X + (ss)*32768;         astr = 128; aoff = kc_;       at_ = false; } \
      else           { ap = h0buf + ((ss)&1)*65536; astr = 256; aoff = kc_ - 128; at_ = true; }  \
    } else {                                                                      \
      if (kc_ < 256) { ap = h0buf + ((ss)&1)*65536; astr = 256; aoff = kc_;       at_ = true; }  \
      else           { ap = h1buf + ((ss)&1)*65536; astr = 256; aoff = kc_ - 256; at_ = true; }  \
    }                                                                             \
    const float* base_ = ap + (b0 + bl)*astr + aoff + 4*jq;                       \
    if (at_) {                                                                    \
      float2 p0 = h_load2(base_),     p1 = h_load2(base_ + 2);                    \
      float2 p2 = h_load2(base_ + 8), p3 = h_load2(base_ + 10);                   \
      av0 = make_float4(p0.x, p0.y, p1.x, p1.y);                                  \
      av1 = make_float4(p2.x, p2.y, p3.x, p3.y);                                  \
    } else {                                                                      \
      av0 = *reinterpret_cast<const float4*>(base_);                              \
      av1 = *reinterpret_cast<const float4*>(base_ + 8);                          \
    }                                                                             \
  } while (0)

  // X-sourced chunk-0 waves may prefetch across the barrier (immutable data)
  const bool pf_early = (layer == 0) && (k0w + 16 <= 128);
  if (pf_early) { PF_A(k0w, 0); }

  __syncthreads();   // w_lds ready

#pragma unroll 1
  for (int s = 0; s <= 77; ++s) {
    const bool active = layer ? (s >= 1) : (s < 77);
    if (active) {
      if (!pf_early) { PF_A(k0w, s); }   // h-sourced: after barrier observation
      float acc[4][8];
#pragma unroll
      for (int i = 0; i < 4; ++i)
#pragma unroll
        for (int j = 0; j < 8; ++j) acc[i][j] = 0.f;

#pragma unroll 1
      for (int sc = 0; sc < NSC; ++sc) {
        float* awc = aw + ((sc & 1) << 9);   // double-buffer half
        awc[(4*jq+0)*32 + bl]  = av0.x;
        awc[(4*jq+1)*32 + bl]  = av0.y;
        awc[(4*jq+2)*32 + bl]  = av0.z;
        awc[(4*jq+3)*32 + bl]  = av0.w;
        awc[(4*jq+8)*32 + bl]  = av1.x;
        awc[(4*jq+9)*32 + bl]  = av1.y;
        awc[(4*jq+10)*32 + bl] = av1.z;
        awc[(4*jq+11)*32 + bl] = av1.w;
        if (sc + 1 < NSC) { PF_A(k0w + 16*(sc+1), s); }
        const float* wk = w_lds + ((k0w + (sc << 4)) << 6);
#pragma unroll
        for (int kl = 0; kl < 16; ++kl) {
          const float4 a4  = *reinterpret_cast<const float4*>(awc + kl*32 + 4*bq);
          const float4 wA  = *reinterpret_cast<const float4*>(wk + (kl<<6) + 8*rq);
          const float4 wB  = *reinterpret_cast<const float4*>(wk + (kl<<6) + 8*rq + 4);
          acc[0][0] += a4.x*wA.x; acc[0][1] += a4.x*wA.y; acc[0][2] += a4.x*wA.z; acc[0][3] += a4.x*wA.w;
          acc[0][4] += a4.x*wB.x; acc[0][5] += a4.x*wB.y; acc[0][6] += a4.x*wB.z; acc[0][7] += a4.x*wB.w;
          acc[1][0] += a4.y*wA.x; acc[1][1] += a4.y*wA.y; acc[1][2] += a4.y*wA.z; acc[1][3] += a4.y*wA.w;
          acc[1][4] += a4.y*wB.x; acc[1][5] += a4.y*wB.y; acc[1][6] += a4.y*wB.z; acc[1][7] += a4.y*wB.w;
          acc[2][0] += a4.z*wA.x; acc[2][1] += a4.z*wA.y; acc[2][2] += a4.z*wA.z; acc[2][3] += a4.z*wA.w;
          acc[2][4] += a4.z*wB.x; acc[2][5] += a4.z*wB.y; acc[2][6] += a4.z*wB.z; acc[2][7] += a4.z*wB.w;
          acc[3][0] += a4.w*wA.x; acc[3][1] += a4.w*wA.y; acc[3][2] += a4.w*wA.z; acc[3][3] += a4.w*wA.w;
          acc[3][4] += a4.w*wB.x; acc[3][5] += a4.w*wB.y; acc[3][6] += a4.w*wB.z; acc[3][7] += a4.w*wB.w;
        }
      }

      // ---- cross-wave K reduction: w3 -> w2 -> w1 -> w0 (8KB in-place) ----
      __syncthreads();
      if (wv == 3) {
#pragma unroll
        for (int qi = 0; qi < 8; ++qi) {
          const int bi = qi >> 1, c0 = (qi & 1) << 2;
          *reinterpret_cast<float4*>(&red[((qi<<6) + lane) << 2]) =
            make_float4(acc[bi][c0], acc[bi][c0+1], acc[bi][c0+2], acc[bi][c0+3]);
        }
      }
      __syncthreads();
      if (wv == 2) {
#pragma unroll
        for (int qi = 0; qi < 8; ++qi) {
          const int bi = qi >> 1, c0 = (qi & 1) << 2;
          float4 v = *reinterpret_cast<const float4*>(&red[((qi<<6) + lane) << 2]);
          *reinterpret_cast<float4*>(&red[((qi<<6) + lane) << 2]) =
            make_float4(acc[bi][c0]+v.x, acc[bi][c0+1]+v.y, acc[bi][c0+2]+v.z, acc[bi][c0+3]+v.w);
        }
      }
      __syncthreads();
      if (wv == 1) {
#pragma unroll
        for (int qi = 0; qi < 8; ++qi) {
          const int bi = qi >> 1, c0 = (qi & 1) << 2;
          float4 v = *reinterpret_cast<const float4*>(&red[((qi<<6) + lane) << 2]);
          *reinterpret_cast<float4*>(&red[((qi<<6) + lane) << 2]) =
            make_float4(acc[bi][c0]+v.x, acc[bi][c0+1]+v.y, acc[bi][c0+2]+v.z, acc[bi][c0+3]+v.w);
        }
      }
      __syncthreads();
      if (wv == 0) {
#pragma unroll
        for (int qi = 0; qi < 8; ++qi) {
          const int bi = qi >> 1, c0 = (qi & 1) << 2;
          float4 v = *reinterpret_cast<const float4*>(&red[((qi<<6) + lane) << 2]);
          acc[bi][c0]   += v.x;
          acc[bi][c0+1] += v.y;
          acc[bi][c0+2] += v.z;
          acc[bi][c0+3] += v.w;
        }
        float* __restrict__ hw = (layer ? h1buf : h0buf) + ((s+1)&1)*65536;
#pragma unroll
        for (int bi = 0; bi < 4; ++bi) {
          float hv[2];
#pragma unroll
          for (int uj = 0; uj < 2; ++uj) {
            float gi = acc[bi][4*uj+0] + bsum[uj][0];
            float gf = acc[bi][4*uj+1] + bsum[uj][1];
            float gg = acc[bi][4*uj+2] + bsum[uj][2];
            float go = acc[bi][4*uj+3] + bsum[uj][3];
            float si = 1.f/(1.f + expf(-gi));
            float sf = 1.f/(1.f + expf(-gf));
            float so = 1.f/(1.f + expf(-go));
            float tg = tanhf(gg);
            float cn = sf*c_reg[uj][bi] + si*tg;
            c_reg[uj][bi] = cn;
            hv[uj] = so*tanhf(cn);
          }
          h_store2(hw + (b0 + 4*bq + bi)*256 + u0 + 2*rq, hv[0], hv[1]);
        }
        // no fence: stores are agent-scope sc1 atomics (coherent at L3); the
        // vmcnt(0) drain inside the next __syncthreads orders them before the
        // slot release below (wave0 program order).
      }
    }
    if (s == 77) break;
    __syncthreads();                // all waves done; drains wave0's h-stores
    if (tid == 0)
      __hip_atomic_store(slot, (unsigned)(s+1), __ATOMIC_RELAXED, __HIP_MEMORY_SCOPE_AGENT);
    // pre-spin prefetch of next step's chunk-0 A for X-sourced waves (race-free)
    if (pf_early && (s + 1 < 77)) { PF_A(k0w, s + 1); }
    if (wv == 0) {
      const unsigned tgt = (unsigned)(s+1);
      for (;;) {
        unsigned v = tgt;
        if (lane < 32)
          v = __hip_atomic_load(gbase + (lane << 4), __ATOMIC_RELAXED, __HIP_MEMORY_SCOPE_AGENT);
        if (__all(v >= tgt)) break;
        __builtin_amdgcn_s_sleep(2);
      }
      asm volatile("" ::: "memory");   // compiler barrier: no hoisting h-loads above spin
    }
    __syncthreads();
    if (layer == 1) {
      const int ns = s + 1;
      if (ns >= 1 && ns <= 77) PF_A(0, ns);   // h0-sourced: after barrier observation
    }
  }
#undef PF_A
}

// ---------------- FC: C = act(A @ W^T + b), M=256 ----------------
__global__ __launch_bounds__(256) void k_fc(const float* __restrict__ A,
    const float* __restrict__ W, const float* __restrict__ bias,
    float* __restrict__ Cout, int N, int K, int kshift, int dorelu) {
  __shared__ __align__(16) float sa[16*516];
  int m0 = blockIdx.y * 16;
  int n = blockIdx.x * 16 + (threadIdx.x & 15);
  int m = threadIdx.x >> 4;
  int stride = K + 4;
  for (int i = threadIdx.x; i < 16*K; i += 256) {
    int mm = i >> kshift;
    int kk = i - (mm << kshift);
    sa[mm*stride + kk] = A[(m0+mm)*K + kk];
  }
  __syncthreads();
  const float4* wr = reinterpret_cast<const float4*>(W + n*K);
  const float4* ar = reinterpret_cast<const float4*>(sa + m*stride);
  float acc = 0.f;
  int kq4 = K >> 2;
  for (int kq = 0; kq < kq4; ++kq) {
    float4 wv = wr[kq], av = ar[kq];
    acc += av.x*wv.x + av.y*wv.y + av.z*wv.z + av.w*wv.w;
  }
  acc += bias[n];
  if (dorelu) acc = fmaxf(acc, 0.f);
  Cout[(m0+m)*N + n] = acc;
}

extern "C" void kernel_launch(void* const* d_in, const int* in_sizes, int n_in,
                              void* d_out, int out_size, void* d_ws, size_t ws_size,
                              hipStream_t stream) {
  const float* x       = (const float*)d_in[0];
  const float* conv_w0 = (const float*)d_in[1];
  const float* conv_b0 = (const float*)d_in[2];
  const float* bn_g0   = (const float*)d_in[3];
  const float* bn_b0   = (const float*)d_in[4];
  const float* bn_m0   = (const float*)d_in[5];
  const float* bn_v0   = (const float*)d_in[6];
  const float* conv_w1 = (const float*)d_in[7];
  const float* conv_b1 = (const float*)d_in[8];
  const float* bn_g1   = (const float*)d_in[9];
  const float* bn_b1   = (const float*)d_in[10];
  const float* bn_m1   = (const float*)d_in[11];
  const float* bn_v1   = (const float*)d_in[12];
  const float* Wih0    = (const float*)d_in[13];
  const float* Whh0    = (const float*)d_in[14];
  const float* bih0    = (const float*)d_in[15];
  const float* bhh0    = (const float*)d_in[16];
  const float* Wih1    = (const float*)d_in[17];
  const float* Whh1    = (const float*)d_in[18];
  const float* bih1    = (const float*)d_in[19];
  const float* bhh1    = (const float*)d_in[20];
  const float* fc0_w   = (const float*)d_in[21];
  const float* fc0_b   = (const float*)d_in[22];
  const float* fc1_w   = (const float*)d_in[23];
  const float* fc1_b   = (const float*)d_in[24];
  const float* out_w   = (const float*)d_in[25];
  const float* out_b   = (const float*)d_in[26];
  float* ws = (float*)d_ws;
  float* out = (float*)d_out;

  static float h_consts[160];
  compute_consts(h_consts);
  hipMemcpyAsync(ws + OFF_CONST, h_consts, 160*sizeof(float), hipMemcpyHostToDevice, stream);
  hipMemsetAsync(ws + OFF_H0, 0, 393216*sizeof(float), stream);
  hipMemsetAsync(ws + OFF_BAR, 0, 16384, stream);   // barrier slot lines -> 0

  k_sgconv0<<<dim3(3, BATCH), 256, 0, stream>>>(x, ws + OFF_CONST, conv_w0, conv_b0,
                                                bn_g0, bn_b0, bn_m0, bn_v0, ws + OFF_Y1);
  k_conv1_gemm<<<620, 256, 0, stream>>>(ws + OFF_Y1, conv_w1, conv_b1, ws + OFF_TMP);
  k_pool1<<<9856, 256, 0, stream>>>(ws + OFF_TMP, bn_g1, bn_b1, bn_m1, bn_v1, ws + OFF_X);
  k_lstm_persist<<<256, 256, 0, stream>>>(ws + OFF_X, Wih0, Whh0, bih0, bhh0,
                                          Wih1, Whh1, bih1, bhh1,
                                          ws + OFF_H0, ws + OFF_H1,
                                          (unsigned*)(ws + OFF_BAR));
  k_fc<<<dim3(32, 16), 256, 0, stream>>>(ws + OFF_H1, fc0_w, fc0_b, ws + OFF_Z0, 512, 256, 8, 1);
  k_fc<<<dim3(32, 16), 256, 0, stream>>>(ws + OFF_Z0, fc1_w, fc1_b, ws + OFF_Z1, 512, 512, 9, 1);
  k_fc<<<dim3(16, 16), 256, 0, stream>>>(ws + OFF_Z1, out_w, out_b, out, 256, 512, 9, 0);
}